// Round 1
// baseline (759.541 us; speedup 1.0000x reference)
//
#include <hip/hip_runtime.h>
#include <hip/hip_bf16.h>

#define N_NODES 100000
#define N_EDGES 1600000
#define NEG_SLOPE 0.2f

// ---------------- precompute M1[16][8], M2[16] ----------------
__global__ void k_pre(const float* __restrict__ We1, const float* __restrict__ attE1,
                      const float* __restrict__ We2, const float* __restrict__ attE2,
                      float* __restrict__ M1, float* __restrict__ M2) {
    int t = threadIdx.x;
    if (t < 128) {
        int d = t >> 3, h = t & 7;
        float s = 0.f;
        for (int c = 0; c < 16; ++c) s += We1[d * 128 + h * 16 + c] * attE1[h * 16 + c];
        M1[d * 8 + h] = s;   // layout [d][h]
    } else if (t < 144) {
        int d = t - 128;
        float s = 0.f;
        for (int c = 0; c < 16; ++c) s += We2[d * 16 + c] * attE2[c];
        M2[d] = s;
    }
}

// ---------------- GEMM1: xh1 = x @ W1, plus a1s/a1d ----------------
// block 256: ty=tid/32 (8), tx=tid%32 (col group of 4). 16 rows/block (ty, ty+8).
__global__ __launch_bounds__(256) void k_gemm1(
    const float* __restrict__ x, const float* __restrict__ W1,
    const float* __restrict__ attS, const float* __restrict__ attD,
    float* __restrict__ xh1, float* __restrict__ a1s, float* __restrict__ a1d) {
    __shared__ float Ws[128 * 128];
    int tid = threadIdx.x;
    for (int i = tid * 4; i < 16384; i += 1024)
        *(float4*)(Ws + i) = *(const float4*)(W1 + i);
    __syncthreads();
    int tx = tid & 31, ty = tid >> 5;
    int r0 = blockIdx.x * 16 + ty;     // and r0+8
    int c0 = tx * 4;
    const float* xr0 = x + (size_t)r0 * 128;
    const float* xr1 = xr0 + 8 * 128;
    float acc0[4] = {0.f, 0.f, 0.f, 0.f};
    float acc1[4] = {0.f, 0.f, 0.f, 0.f};
    for (int k = 0; k < 128; k += 4) {
        float4 xa4 = *(const float4*)(xr0 + k);
        float4 xb4 = *(const float4*)(xr1 + k);
        float xa[4] = {xa4.x, xa4.y, xa4.z, xa4.w};
        float xb[4] = {xb4.x, xb4.y, xb4.z, xb4.w};
#pragma unroll
        for (int j = 0; j < 4; ++j) {
            float4 w = *(const float4*)(Ws + (k + j) * 128 + c0);
            acc0[0] += xa[j] * w.x; acc0[1] += xa[j] * w.y;
            acc0[2] += xa[j] * w.z; acc0[3] += xa[j] * w.w;
            acc1[0] += xb[j] * w.x; acc1[1] += xb[j] * w.y;
            acc1[2] += xb[j] * w.z; acc1[3] += xb[j] * w.w;
        }
    }
    float4 o0 = {acc0[0], acc0[1], acc0[2], acc0[3]};
    float4 o1 = {acc1[0], acc1[1], acc1[2], acc1[3]};
    *(float4*)(xh1 + (size_t)r0 * 128 + c0) = o0;
    *(float4*)(xh1 + (size_t)(r0 + 8) * 128 + c0) = o1;
    // per-head attention dots
    int h = tx >> 2;
    int cc = (tx & 3) * 4;
    float ps0 = 0.f, pd0 = 0.f, ps1 = 0.f, pd1 = 0.f;
#pragma unroll
    for (int j = 0; j < 4; ++j) {
        float aS = attS[h * 16 + cc + j];
        float aD = attD[h * 16 + cc + j];
        ps0 += acc0[j] * aS; pd0 += acc0[j] * aD;
        ps1 += acc1[j] * aS; pd1 += acc1[j] * aD;
    }
    ps0 += __shfl_xor(ps0, 1); ps0 += __shfl_xor(ps0, 2);
    pd0 += __shfl_xor(pd0, 1); pd0 += __shfl_xor(pd0, 2);
    ps1 += __shfl_xor(ps1, 1); ps1 += __shfl_xor(ps1, 2);
    pd1 += __shfl_xor(pd1, 1); pd1 += __shfl_xor(pd1, 2);
    if ((tx & 3) == 0) {
        a1s[(size_t)r0 * 8 + h] = ps0;       a1d[(size_t)r0 * 8 + h] = pd0;
        a1s[(size_t)(r0 + 8) * 8 + h] = ps1; a1d[(size_t)(r0 + 8) * 8 + h] = pd1;
    }
}

// ---------------- CSR build ----------------
__global__ void k_hist(const int* __restrict__ dst, int* __restrict__ count) {
    int i = blockIdx.x * blockDim.x + threadIdx.x;
    if (i < N_EDGES) atomicAdd(&count[dst[i]], 1);
}

__global__ __launch_bounds__(256) void k_scan1(const int* __restrict__ count,
                                               int* __restrict__ offs, int* __restrict__ partials) {
    __shared__ int s[256];
    int t = threadIdx.x;
    int i = blockIdx.x * 256 + t;
    int v = (i < N_NODES) ? count[i] : 0;
    s[t] = v; __syncthreads();
    for (int off = 1; off < 256; off <<= 1) {
        int add = (t >= off) ? s[t - off] : 0;
        __syncthreads();
        s[t] += add; __syncthreads();
    }
    if (i < N_NODES) offs[i] = s[t] - v;
    if (t == 255) partials[blockIdx.x] = s[255];
}

__global__ __launch_bounds__(512) void k_scan2(int* __restrict__ partials, int nb) {
    __shared__ int s[512];
    int t = threadIdx.x;
    int v = (t < nb) ? partials[t] : 0;
    s[t] = v; __syncthreads();
    for (int off = 1; off < 512; off <<= 1) {
        int add = (t >= off) ? s[t - off] : 0;
        __syncthreads();
        s[t] += add; __syncthreads();
    }
    if (t < nb) partials[t] = s[t] - v;
}

__global__ void k_scan3(int* __restrict__ offs, const int* __restrict__ partials) {
    int i = blockIdx.x * 256 + threadIdx.x;
    if (i < N_NODES) offs[i] += partials[blockIdx.x];
}

// ---------------- edge kernel: ew1 (CSR order), csr_src, ae2 ----------------
__global__ __launch_bounds__(256) void k_edge(
    const int* __restrict__ src, const int* __restrict__ dst,
    const float* __restrict__ ea, const float* __restrict__ M1, const float* __restrict__ M2,
    const float* __restrict__ a1s, const float* __restrict__ a1d,
    const int* __restrict__ offs, int* __restrict__ cursor,
    int* __restrict__ csr_src, float* __restrict__ ew1, float* __restrict__ ae2) {
    __shared__ float M1s[128], M2s[16];
    int t = threadIdx.x;
    if (t < 128) M1s[t] = M1[t];
    if (t >= 128 && t < 144) M2s[t - 128] = M2[t - 128];
    __syncthreads();
    int e = blockIdx.x * 256 + t;
    if (e >= N_EDGES) return;
    int s = src[e], d = dst[e];
    float eav[16];
#pragma unroll
    for (int q = 0; q < 4; ++q) {
        float4 v = *(const float4*)(ea + (size_t)e * 16 + q * 4);
        eav[q * 4] = v.x; eav[q * 4 + 1] = v.y; eav[q * 4 + 2] = v.z; eav[q * 4 + 3] = v.w;
    }
    float ae1[8];
#pragma unroll
    for (int h = 0; h < 8; ++h) ae1[h] = 0.f;
#pragma unroll
    for (int dd = 0; dd < 16; ++dd) {
#pragma unroll
        for (int h = 0; h < 8; ++h) ae1[h] += eav[dd] * M1s[dd * 8 + h];
    }
    float aes = 0.f;
#pragma unroll
    for (int dd = 0; dd < 16; ++dd) aes += eav[dd] * M2s[dd];
    float4 s0 = *(const float4*)(a1s + (size_t)s * 8);
    float4 s1 = *(const float4*)(a1s + (size_t)s * 8 + 4);
    float4 d0 = *(const float4*)(a1d + (size_t)d * 8);
    float4 d1 = *(const float4*)(a1d + (size_t)d * 8 + 4);
    float as_[8] = {s0.x, s0.y, s0.z, s0.w, s1.x, s1.y, s1.z, s1.w};
    float ad_[8] = {d0.x, d0.y, d0.z, d0.w, d1.x, d1.y, d1.z, d1.w};
    int p = offs[d] + atomicAdd(&cursor[d], 1);
    float ew[8];
#pragma unroll
    for (int h = 0; h < 8; ++h) {
        float v = as_[h] + ad_[h] + ae1[h];
        v = v > 0.f ? v : NEG_SLOPE * v;
        ew[h] = __expf(v);
    }
    float4 w0 = {ew[0], ew[1], ew[2], ew[3]};
    float4 w1 = {ew[4], ew[5], ew[6], ew[7]};
    *(float4*)(ew1 + (size_t)p * 8) = w0;
    *(float4*)(ew1 + (size_t)p * 8 + 4) = w1;
    csr_src[p] = s;
    ae2[p] = aes;
}

// ---------------- layer-1 aggregation: block per node, 128 threads ----------------
__global__ __launch_bounds__(128) void k_agg1(
    const int* __restrict__ csr_src, const float* __restrict__ ew1,
    const float* __restrict__ xh1, const int* __restrict__ offs, const int* __restrict__ count,
    const float* __restrict__ b1, float* __restrict__ h1) {
    int n = blockIdx.x;
    int c = threadIdx.x;
    int h = c >> 4;
    int start = offs[n], deg = count[n];
    float acc = 0.f, wsum = 0.f;
    int i = 0;
    for (; i + 4 <= deg; i += 4) {
        int p = start + i;
        int s0 = csr_src[p], s1 = csr_src[p + 1], s2 = csr_src[p + 2], s3 = csr_src[p + 3];
        float e0 = ew1[(size_t)p * 8 + h],       e1 = ew1[(size_t)(p + 1) * 8 + h];
        float e2 = ew1[(size_t)(p + 2) * 8 + h], e3 = ew1[(size_t)(p + 3) * 8 + h];
        float x0 = xh1[(size_t)s0 * 128 + c], x1 = xh1[(size_t)s1 * 128 + c];
        float x2 = xh1[(size_t)s2 * 128 + c], x3 = xh1[(size_t)s3 * 128 + c];
        acc += e0 * x0; acc += e1 * x1; acc += e2 * x2; acc += e3 * x3;
        wsum += e0 + e1 + e2 + e3;
    }
    for (; i < deg; ++i) {
        int p = start + i;
        int s = csr_src[p];
        float e = ew1[(size_t)p * 8 + h];
        acc += e * xh1[(size_t)s * 128 + c];
        wsum += e;
    }
    float v = acc / (wsum + 1e-16f) + b1[c];
    h1[(size_t)n * 128 + c] = v > 0.f ? v : __expf(v) - 1.f;
}

// ---------------- GEMM2: xh2 = h1 @ W2, plus a2s/a2d ----------------
__global__ __launch_bounds__(256) void k_gemm2(
    const float* __restrict__ h1, const float* __restrict__ W2,
    const float* __restrict__ attS, const float* __restrict__ attD,
    float* __restrict__ xh2, float* __restrict__ a2s, float* __restrict__ a2d) {
    __shared__ float W2s[128 * 16];
    __shared__ float hs[16 * 132];   // +4 pad to break bank conflicts
    int t = threadIdx.x;
    for (int i = t * 4; i < 2048; i += 1024)
        *(float4*)(W2s + i) = *(const float4*)(W2 + i);
    size_t base = (size_t)blockIdx.x * 16 * 128;
    for (int i = t * 4; i < 2048; i += 1024) {
        float4 v = *(const float4*)(h1 + base + i);
        int r = i >> 7, k = i & 127;
        float* dstp = hs + r * 132 + k;
        dstp[0] = v.x; dstp[1] = v.y; dstp[2] = v.z; dstp[3] = v.w;
    }
    __syncthreads();
    int r = t >> 4, c = t & 15;
    float acc = 0.f;
#pragma unroll 4
    for (int k = 0; k < 128; ++k) acc += hs[r * 132 + k] * W2s[k * 16 + c];
    int row = blockIdx.x * 16 + r;
    xh2[(size_t)row * 16 + c] = acc;
    float ps = acc * attS[c], pd = acc * attD[c];
#pragma unroll
    for (int m = 1; m < 16; m <<= 1) { ps += __shfl_xor(ps, m); pd += __shfl_xor(pd, m); }
    if (c == 0) { a2s[row] = ps; a2d[row] = pd; }
}

// ---------------- layer-2 aggregation + bias + log_softmax ----------------
__global__ __launch_bounds__(64) void k_agg2(
    const int* __restrict__ csr_src, const float* __restrict__ ae2,
    const float* __restrict__ a2s, const float* __restrict__ a2d, const float* __restrict__ xh2,
    const int* __restrict__ offs, const int* __restrict__ count,
    const float* __restrict__ b2, float* __restrict__ out) {
    int n = blockIdx.x;
    int t = threadIdx.x;
    int j = t >> 4, c = t & 15;
    int start = offs[n], deg = count[n];
    float ad = a2d[n];
    float acc = 0.f, wsum = 0.f;
    for (int i = j; i < deg; i += 4) {
        int p = start + i;
        int s = csr_src[p];
        float lg = a2s[s] + ad + ae2[p];
        lg = lg > 0.f ? lg : NEG_SLOPE * lg;
        float e = __expf(lg);
        acc += e * xh2[(size_t)s * 16 + c];
        wsum += e;
    }
    acc += __shfl_xor(acc, 16);  acc += __shfl_xor(acc, 32);
    wsum += __shfl_xor(wsum, 16); wsum += __shfl_xor(wsum, 32);
    float logit = acc / (wsum + 1e-16f) + b2[c];
    float m = logit;
#pragma unroll
    for (int mm = 1; mm < 16; mm <<= 1) m = fmaxf(m, __shfl_xor(m, mm));
    float ex = __expf(logit - m);
#pragma unroll
    for (int mm = 1; mm < 16; mm <<= 1) ex += __shfl_xor(ex, mm);
    float res = logit - m - __logf(ex);
    if (t < 16) out[(size_t)n * 16 + c] = res;
}

extern "C" void kernel_launch(void* const* d_in, const int* in_sizes, int n_in,
                              void* d_out, int out_size, void* d_ws, size_t ws_size,
                              hipStream_t stream) {
    const float* x     = (const float*)d_in[0];
    const int*   ei    = (const int*)d_in[1];
    const float* ea    = (const float*)d_in[2];
    const float* W1    = (const float*)d_in[3];
    const float* attS1 = (const float*)d_in[4];
    const float* attD1 = (const float*)d_in[5];
    const float* We1   = (const float*)d_in[6];
    const float* attE1 = (const float*)d_in[7];
    const float* b1    = (const float*)d_in[8];
    const float* W2    = (const float*)d_in[9];
    const float* attS2 = (const float*)d_in[10];
    const float* attD2 = (const float*)d_in[11];
    const float* We2   = (const float*)d_in[12];
    const float* attE2 = (const float*)d_in[13];
    const float* b2    = (const float*)d_in[14];
    float* out = (float*)d_out;
    const int* src = ei;
    const int* dst = ei + N_EDGES;

    char* p = (char*)d_ws;
    auto alloc = [&](size_t bytes) { char* r = p; p += (bytes + 255) & ~(size_t)255; return r; };
    float* xh1      = (float*)alloc((size_t)N_NODES * 128 * 4);
    float* h1       = (float*)alloc((size_t)N_NODES * 128 * 4);
    float* ew1      = (float*)alloc((size_t)N_EDGES * 8 * 4);
    float* a1s      = (float*)alloc((size_t)N_NODES * 8 * 4);
    float* a1d      = (float*)alloc((size_t)N_NODES * 8 * 4);
    float* xh2      = (float*)alloc((size_t)N_NODES * 16 * 4);
    float* a2s      = (float*)alloc((size_t)N_NODES * 4);
    float* a2d      = (float*)alloc((size_t)N_NODES * 4);
    float* ae2      = (float*)alloc((size_t)N_EDGES * 4);
    int*   csr_src  = (int*)alloc((size_t)N_EDGES * 4);
    int*   count    = (int*)alloc((size_t)N_NODES * 4);
    int*   cursor   = (int*)alloc((size_t)N_NODES * 4);   // contiguous after count
    int*   offs     = (int*)alloc((size_t)(N_NODES + 1) * 4);
    int*   partials = (int*)alloc(1024 * 4);
    float* M1       = (float*)alloc(128 * 4);
    float* M2       = (float*)alloc(64 * 4);
    if ((size_t)(p - (char*)d_ws) > ws_size) return;  // workspace too small — fail visibly

    const int nb_scan = (N_NODES + 255) / 256;  // 391

    hipMemsetAsync(count, 0, (size_t)2 * N_NODES * 4 + 256, stream);  // count + cursor
    k_pre<<<1, 192, 0, stream>>>(We1, attE1, We2, attE2, M1, M2);
    k_gemm1<<<N_NODES / 16, 256, 0, stream>>>(x, W1, attS1, attD1, xh1, a1s, a1d);
    k_hist<<<(N_EDGES + 255) / 256, 256, 0, stream>>>(dst, count);
    k_scan1<<<nb_scan, 256, 0, stream>>>(count, offs, partials);
    k_scan2<<<1, 512, 0, stream>>>(partials, nb_scan);
    k_scan3<<<nb_scan, 256, 0, stream>>>(offs, partials);
    k_edge<<<(N_EDGES + 255) / 256, 256, 0, stream>>>(src, dst, ea, M1, M2, a1s, a1d,
                                                      offs, cursor, csr_src, ew1, ae2);
    k_agg1<<<N_NODES, 128, 0, stream>>>(csr_src, ew1, xh1, offs, count, b1, h1);
    k_gemm2<<<N_NODES / 16, 256, 0, stream>>>(h1, W2, attS2, attD2, xh2, a2s, a2d);
    k_agg2<<<N_NODES, 64, 0, stream>>>(csr_src, ae2, a2s, a2d, xh2, offs, count, b2, out);
}